// Round 2
// baseline (305.723 us; speedup 1.0000x reference)
//
#include <hip/hip_runtime.h>

// MixSelfAttention (B=2, L=1024, H=8, E=64), float32 in/out.
//
// Decomposition:
//   K1: circular cross-correlation ac[tau,e] = sum_t Q[(t+tau)%L,e]K[t,e];
//       per (bh, eg of 4 e's): amp2part[bh][eg][tau] = sum_{e in eg} ac^2
//   K3: top-35 indices per (bh) for both branches (t: sum amp2part over eg;
//       tf: row norms of tf_queries), jax tie-break (smallest index first)
//   K4: 70 sparse scores per row m + softmax -> P[bh][m][72]
//   K5: WV[bh][j][d] = sum_m W[m,col_j] * v[b,m,h,d]  (j=70 -> bias row)
//   K6: out[b,l,h,d] = sum_j P[l,j]*WV[j,d] + WV[70,d]
//
// ws map (bytes): amp2part 1M | St 4K | Stf 4K | P 4.5M | WV 288K  (~5.8 MB)

#define NTOP 35
#define NJ 70

static __device__ __forceinline__ void fma4(float4& a, float4 q, float4 k) {
  a.x = fmaf(q.x,k.x,a.x); a.y = fmaf(q.y,k.y,a.y);
  a.z = fmaf(q.z,k.z,a.z); a.w = fmaf(q.w,k.w,a.w);
}

// ---------------- K1: correlation, rolling registers ----------------
// grid 256 = 16 bh x 16 eg, block 256. LDS-staged Q (pad-swizzled) and K.
__global__ __launch_bounds__(256) void k1_corr(
    const float* __restrict__ q, const float* __restrict__ k,
    float* __restrict__ amp2part) {
  int gid = blockIdx.x;
  int bh = gid & 15;  int eg = gid >> 4;
  int b = bh >> 3, h = bh & 7;
  __shared__ float4 Ks[1024];
  __shared__ float4 Qs[1024 + 128];     // pad-swizzled: phys = r + (r>>3)
  int tid = threadIdx.x;
  size_t base = ((size_t)b*1024*8 + h)*64 + eg*4;   // element offset; +t*512 per row
  for (int r = tid; r < 1024; r += 256) {
    float4 qv = *reinterpret_cast<const float4*>(q + base + (size_t)r*512);
    float4 kv = *reinterpret_cast<const float4*>(k + base + (size_t)r*512);
    Qs[r + (r >> 3)] = qv;
    Ks[r] = kv;
  }
  __syncthreads();
  int tb = tid << 2;                    // 4 consecutive tau per thread
  float4 a0 = make_float4(0,0,0,0), a1 = a0, a2 = a0, a3 = a0;
  int r0 = tb, r1 = tb+1, r2 = tb+2, r3 = tb+3;
  float4 q0 = Qs[r0 + (r0>>3)], q1 = Qs[r1 + (r1>>3)];
  float4 q2 = Qs[r2 + (r2>>3)], q3 = Qs[r3 + (r3>>3)];
  #pragma unroll 4
  for (int t = 0; t < 1024; ++t) {
    float4 kv = Ks[t];
    fma4(a0, q0, kv); fma4(a1, q1, kv); fma4(a2, q2, kv); fma4(a3, q3, kv);
    q0 = q1; q1 = q2; q2 = q3;
    int rn = (t + tb + 4) & 1023;
    q3 = Qs[rn + (rn >> 3)];
  }
  float4 r;
  r.x = a0.x*a0.x + a0.y*a0.y + a0.z*a0.z + a0.w*a0.w;
  r.y = a1.x*a1.x + a1.y*a1.y + a1.z*a1.z + a1.w*a1.w;
  r.z = a2.x*a2.x + a2.y*a2.y + a2.z*a2.z + a2.w*a2.w;
  r.w = a3.x*a3.x + a3.y*a3.y + a3.z*a3.z + a3.w*a3.w;
  reinterpret_cast<float4*>(amp2part + (size_t)(bh*16+eg)*1024)[tid] = r;
}

// ---------------- K3: top-35 (blocks 0..15: t-branch, 16..31: tf) ----------------
__global__ __launch_bounds__(256) void k3_topk(
    const float* __restrict__ amp2part, const float* __restrict__ tfq,
    int* __restrict__ St, int* __restrict__ Stf) {
  int bid = blockIdx.x;
  bool isT = bid < 16;
  int bh = isT ? bid : bid - 16;
  __shared__ float vals[1024];
  __shared__ long long wred[4];
  int tid = threadIdx.x;
  if (isT) {
    for (int l = tid; l < 1024; l += 256) {
      float s = 0.f;
      #pragma unroll
      for (int eg = 0; eg < 16; ++eg)
        s += amp2part[((size_t)bh*16 + eg)*1024 + l];
      vals[l] = s;
    }
  } else {
    int b = bh >> 3, h = bh & 7;
    for (int l = tid; l < 1024; l += 256) {
      const float4* p = reinterpret_cast<const float4*>(
          tfq + (((size_t)(b*1024 + l)*8 + h) << 6));
      float s = 0.f;
      #pragma unroll
      for (int i = 0; i < 16; ++i) {
        float4 v = p[i];
        s += v.x*v.x + v.y*v.y + v.z*v.z + v.w*v.w;
      }
      vals[l] = s;
    }
  }
  __syncthreads();
  int* out = isT ? (St + bh*40) : (Stf + bh*40);
  for (int it = 0; it < NTOP; ++it) {
    long long best = -0x7FFFFFFFFFFFFFFFLL - 1;
    for (int l = tid; l < 1024; l += 256) {
      long long key = ((long long)(int)__float_as_uint(vals[l]) << 32)
                      | (unsigned int)(1023 - l);
      if (key > best) best = key;
    }
    for (int off = 32; off; off >>= 1) {
      long long o = __shfl_down(best, off);
      if (o > best) best = o;
    }
    if ((tid & 63) == 0) wred[tid >> 6] = best;
    __syncthreads();
    if (tid == 0) {
      long long bb = wred[0];
      for (int w = 1; w < 4; ++w) if (wred[w] > bb) bb = wred[w];
      int idx = 1023 - (int)(bb & 0xFFFFFFFFLL);
      out[it] = idx;
      vals[idx] = -1.0f;                // killed: negative, never re-selected
    }
    __syncthreads();
  }
}

// ---------------- K4: sparse scores + softmax -> P[bh][m][72] ----------------
__global__ __launch_bounds__(64) void k4_scores(
    const float* __restrict__ q, const float* __restrict__ k,
    const float* __restrict__ tfq,
    const int* __restrict__ St, const int* __restrict__ Stf,
    float* __restrict__ P) {
  int gid = blockIdx.x;                 // 256 = 16 bh x 16 mchunk
  int bh = gid >> 4;  int m0 = (gid & 15) << 6;
  int b = bh >> 3, h = bh & 7;
  __shared__ float qs[NTOP*64];
  __shared__ float ts[NTOP*64];
  __shared__ float sc[64*72];
  int tid = threadIdx.x;                // 64
  for (int i = tid; i < NTOP*64; i += 64) {
    int j = i >> 6, e = i & 63;
    int rq = St[bh*40 + j];
    int rt = Stf[bh*40 + j];
    qs[i] = q  [(((size_t)(b*1024 + rq)*8 + h) << 6) + e];
    ts[i] = tfq[(((size_t)(b*1024 + rt)*8 + h) << 6) + e];
  }
  __syncthreads();
  int m = m0 + tid;
  float4 kr[16];
  {
    const float4* p = reinterpret_cast<const float4*>(
        k + (((size_t)(b*1024 + m)*8 + h) << 6));
    #pragma unroll
    for (int i = 0; i < 16; ++i) kr[i] = p[i];
  }
  const float4* qs4 = reinterpret_cast<const float4*>(qs);
  for (int j = 0; j < NTOP; ++j) {
    float s = 0.f;
    #pragma unroll
    for (int e4 = 0; e4 < 16; ++e4) {
      float4 qv = qs4[j*16 + e4];
      s += qv.x*kr[e4].x + qv.y*kr[e4].y + qv.z*kr[e4].z + qv.w*kr[e4].w;
    }
    sc[tid*72 + j] = s * 0.125f;
  }
  {
    const float4* p = reinterpret_cast<const float4*>(
        tfq + (((size_t)(b*1024 + m)*8 + h) << 6));
    #pragma unroll
    for (int i = 0; i < 16; ++i) kr[i] = p[i];
  }
  const float4* ts4 = reinterpret_cast<const float4*>(ts);
  for (int j = 0; j < NTOP; ++j) {
    float s = 0.f;
    #pragma unroll
    for (int e4 = 0; e4 < 16; ++e4) {
      float4 qv = ts4[j*16 + e4];
      s += qv.x*kr[e4].x + qv.y*kr[e4].y + qv.z*kr[e4].z + qv.w*kr[e4].w;
    }
    sc[tid*72 + NTOP + j] = s * 0.125f;
  }
  // softmax over the 70 finite entries (rest of row is -inf -> 0)
  float mx = -1e30f;
  for (int j = 0; j < NJ; ++j) mx = fmaxf(mx, sc[tid*72 + j]);
  float sum = 0.f;
  for (int j = 0; j < NJ; ++j) {
    float e = __expf(sc[tid*72 + j] - mx);
    sc[tid*72 + j] = e; sum += e;
  }
  float inv = 1.0f / sum;
  float* Pr = P + ((size_t)bh*1024 + m)*72;
  for (int j = 0; j < NJ; ++j) Pr[j] = sc[tid*72 + j] * inv;
}

// ---------------- K5: WV[bh][j][d] = sum_m W[m,col_j] * v[b,m,h,d] ----------------
__global__ __launch_bounds__(256) void k5_wv(
    const float* __restrict__ w, const float* __restrict__ bias,
    const float* __restrict__ values,
    const int* __restrict__ St, const int* __restrict__ Stf,
    float* __restrict__ WV) {
  int j = blockIdx.x;                   // 0..70
  int bh = blockIdx.y;                  // 0..15
  int b = bh >> 3, h = bh & 7;
  int col;
  if (j < NTOP)      col = St[bh*40 + j];
  else if (j < NJ)   col = 1024 + Stf[bh*40 + j - NTOP];
  else               col = -1;          // bias row
  int tid = threadIdx.x;
  int d = tid & 63, mp = tid >> 6;
  float acc = 0.f;
  for (int m = mp; m < 1024; m += 4) {
    float wv = (col < 0) ? bias[m] : w[(size_t)m*2048 + col];
    float vv = values[(((size_t)(b*1024 + m)*8 + h) << 6) + d];
    acc = fmaf(wv, vv, acc);
  }
  __shared__ float red[256];
  red[tid] = acc;
  __syncthreads();
  if (tid < 64) {
    float s = red[tid] + red[tid+64] + red[tid+128] + red[tid+192];
    WV[((size_t)bh*72 + j)*64 + d] = s;
  }
}

// ---------------- K6: out[b,l,h,d] ----------------
__global__ __launch_bounds__(512) void k6_out(
    const float* __restrict__ P, const float* __restrict__ WV,
    float* __restrict__ out) {
  int l = blockIdx.x, b = blockIdx.y;
  int tid = threadIdx.x;
  int h = tid >> 6, d = tid & 63;
  int bh = b*8 + h;
  const float* Pr = P + ((size_t)bh*1024 + l)*72;
  const float* Wv = WV + (size_t)bh*72*64;
  float acc = Wv[NJ*64 + d];            // bias @ values row
  for (int j = 0; j < NJ; ++j) acc = fmaf(Pr[j], Wv[j*64 + d], acc);
  out[(((size_t)(b*1024 + l)*8 + h) << 6) + d] = acc;
}

extern "C" void kernel_launch(void* const* d_in, const int* in_sizes, int n_in,
                              void* d_out, int out_size, void* d_ws, size_t ws_size,
                              hipStream_t stream) {
  const float* tfq  = (const float*)d_in[0];
  const float* q    = (const float*)d_in[1];
  const float* k    = (const float*)d_in[2];
  const float* v    = (const float*)d_in[3];
  const float* tw   = (const float*)d_in[5];
  const float* tb   = (const float*)d_in[6];
  float* out = (float*)d_out;

  char* ws = (char*)d_ws;
  float* amp2part = (float*)(ws);                        // 1 MB
  int*   St       = (int*)  (ws + (1u<<20));             // 4 KB (16 x stride40)
  int*   Stf      = (int*)  (ws + (1u<<20) + 4096);      // 4 KB
  float* P        = (float*)(ws + (1u<<20) + 8192);      // 16*1024*72*4 = 4718592
  float* WV       = (float*)(ws + (1u<<20) + 8192 + 4718592); // 16*72*64*4

  k1_corr   <<<256, 256, 0, stream>>>(q, k, amp2part);
  k3_topk   <<<32, 256, 0, stream>>>(amp2part, tfq, St, Stf);
  k4_scores <<<256, 64, 0, stream>>>(q, k, tfq, St, Stf, P);
  k5_wv     <<<dim3(71, 16), 256, 0, stream>>>(tw, tb, v, St, Stf, WV);
  k6_out    <<<dim3(1024, 2), 512, 0, stream>>>(P, WV, out);
}